// Round 6
// baseline (1070.947 us; speedup 1.0000x reference)
//
#include <hip/hip_runtime.h>
#include <math.h>

// ---------------------------------------------------------------------------
// SpatialGNN: 3x GCN (residual) + 4-head GAT + MLP + log_softmax
// N=100000, E=1600000, IN=8, HID=64, HEADS=4, OUT=3
//
// R5 changes vs R4:
//  - fp16 gather features: xs/hs1/hs2/h3 stored as _Float16 rows (128 B vs
//    256 B). The GCN/GAT gathers were a random-read byte-traffic wall
//    (FETCH 193MB/layer, L3-bound ~1.2TB/s); fp16 halves the bytes AND
//    shrinks the working set 25.6->12.8MB (better L2 hit rate). All math,
//    weights, accumulators, attention logits stay fp32 (fp16 rounding
//    2^-11 << pass threshold slack).
//  - New lane layout: 16B half8 per lane = 8 edges in flight per wave
//    instruction (vs 4); gat_agg exp redundancy 16x -> 8x; gcn_layer1 row
//    is a single half8 -> one edge per lane, no shfl distribution.
// ---------------------------------------------------------------------------

typedef _Float16 half8 __attribute__((ext_vector_type(8)));

__device__ __forceinline__ float leaky02(float v) { return v > 0.f ? v : 0.2f * v; }

// ---- CSR build ------------------------------------------------------------

__global__ void count_kernel(const int* __restrict__ dst, int E, int* __restrict__ counts) {
    int e = blockIdx.x * blockDim.x + threadIdx.x;
    if (e < E) atomicAdd(&counts[dst[e]], 1);
}

__global__ void scan_pass1(const int* __restrict__ counts, int n, int* __restrict__ blockSums) {
    __shared__ int sh[256];
    int base = blockIdx.x * 2048;
    int tid = threadIdx.x;
    int s = 0;
#pragma unroll
    for (int j = 0; j < 8; ++j) {
        int idx = base + tid * 8 + j;
        if (idx < n) s += counts[idx];
    }
    sh[tid] = s;
    __syncthreads();
    for (int off = 128; off > 0; off >>= 1) {
        if (tid < off) sh[tid] += sh[tid + off];
        __syncthreads();
    }
    if (tid == 0) blockSums[blockIdx.x] = sh[0];
}

__global__ void scan_pass2(const int* __restrict__ blockSums, int nb, int* __restrict__ blockOffs) {
    if (threadIdx.x == 0 && blockIdx.x == 0) {
        int run = 0;
        for (int i = 0; i < nb; ++i) { blockOffs[i] = run; run += blockSums[i]; }
    }
}

// emits dinv, rdinv, and xs = (half8)(dinv * x)
__global__ void scan_pass3(const int* __restrict__ counts, int n,
                           const int* __restrict__ blockOffs,
                           const float* __restrict__ x,
                           int* __restrict__ row_ptr, int* __restrict__ cursor,
                           float* __restrict__ dinv, float* __restrict__ rdinv,
                           _Float16* __restrict__ xs) {
    __shared__ int sh[256];
    int base = blockIdx.x * 2048;
    int tid = threadIdx.x;
    int cnt[8];
    int local = 0;
#pragma unroll
    for (int j = 0; j < 8; ++j) {
        int idx = base + tid * 8 + j;
        cnt[j] = (idx < n) ? counts[idx] : 0;
        local += cnt[j];
    }
    sh[tid] = local;
    __syncthreads();
    for (int off = 1; off < 256; off <<= 1) {
        int v = (tid >= off) ? sh[tid - off] : 0;
        __syncthreads();
        sh[tid] += v;
        __syncthreads();
    }
    int run = blockOffs[blockIdx.x] + sh[tid] - local;
#pragma unroll
    for (int j = 0; j < 8; ++j) {
        int idx = base + tid * 8 + j;
        if (idx < n) {
            row_ptr[idx] = run;
            cursor[idx] = run;
            float dv = rsqrtf((float)(cnt[j] + 1));
            dinv[idx] = dv;
            rdinv[idx] = sqrtf((float)(cnt[j] + 1));
#pragma unroll
            for (int t = 0; t < 8; ++t) xs[idx * 8 + t] = (_Float16)(dv * x[idx * 8 + t]);
            run += cnt[j];
            if (idx == n - 1) row_ptr[n] = run;
        }
    }
}

__global__ void scatter_kernel(const int* __restrict__ src, const int* __restrict__ dst, int E,
                               int* __restrict__ cursor, int* __restrict__ col_src) {
    int e = blockIdx.x * blockDim.x + threadIdx.x;
    if (e < E) {
        int d = dst[e];
        int pos = atomicAdd(&cursor[d], 1);
        col_src[pos] = src[e];
    }
}

// ---- weight precomputes ---------------------------------------------------

__global__ void att_eff_kernel(const float* __restrict__ Wg,
                               const float* __restrict__ att_src, const float* __restrict__ att_dst,
                               float* __restrict__ wsrc_eff, float* __restrict__ wdst_eff) {
    int t = threadIdx.x;
    int k = t >> 2, h = t & 3;
    float ss = 0.f, sd = 0.f;
    for (int c = 0; c < 64; ++c) {
        float w = Wg[k * 256 + h * 64 + c];
        ss += w * att_src[h * 64 + c];
        sd += w * att_dst[h * 64 + c];
    }
    wsrc_eff[k * 4 + h] = ss;
    wdst_eff[k * 4 + h] = sd;
}

__global__ void ccomb_kernel(const float* __restrict__ Wg, const float* __restrict__ bg,
                             const float* __restrict__ wc1, const float* __restrict__ bc1,
                             float* __restrict__ Ccomb, float* __restrict__ bcomb) {
    int bid = blockIdx.x;   // 0..256
    int j = threadIdx.x;    // 64 threads
    if (bid < 256) {
        int h = bid >> 6, k = bid & 63;
        float s = 0.f;
        for (int c = 0; c < 64; ++c)
            s += Wg[k * 256 + h * 64 + c] * wc1[(h * 64 + c) * 64 + j];
        Ccomb[bid * 64 + j] = s;
    } else {
        float s = bc1[j];
        for (int i = 0; i < 256; ++i) s += bg[i] * wc1[i * 64 + j];
        bcomb[j] = s;
    }
}

// ---- GCN layer 1: one edge per lane (16B half8 row) -----------------------

__global__ void gcn_layer1(const half8* __restrict__ xs8,
                           const float* __restrict__ W1, const float* __restrict__ b1,
                           const int* __restrict__ row_ptr, const int* __restrict__ col_src,
                           const float* __restrict__ dinv, int n,
                           _Float16* __restrict__ hs1) {
    int tid = threadIdx.x, lane = tid & 63, wid = tid >> 6;
    int node = blockIdx.x * 4 + wid;
    if (node >= n) return;
    int beg = row_ptr[node], end = row_ptr[node + 1];
    int deg = end - beg;
    float acc[8] = {0.f, 0.f, 0.f, 0.f, 0.f, 0.f, 0.f, 0.f};
    for (int base = 0; base < deg; base += 64) {
        int cs = col_src[min(beg + base + lane, end - 1)];
        half8 v = xs8[cs];
        if (base + lane < deg) {
#pragma unroll
            for (int c = 0; c < 8; ++c) acc[c] += (float)v[c];
        }
    }
#pragma unroll
    for (int m = 32; m > 0; m >>= 1) {
#pragma unroll
        for (int c = 0; c < 8; ++c) acc[c] += __shfl_xor(acc[c], m);
    }
    half8 sv = xs8[node];
    float di = dinv[node];
    float agg[8];
#pragma unroll
    for (int c = 0; c < 8; ++c) agg[c] = (acc[c] + (float)sv[c]) * di;
    float sum = b1[lane];
#pragma unroll
    for (int k = 0; k < 8; ++k) sum = fmaf(agg[k], W1[k * 64 + lane], sum);
    hs1[node * 64 + lane] = (_Float16)(di * fmaxf(sum, 0.f));
}

// ---- GCN layer 2/3: 8 groups x 8 half-channels, 16 edges per chunk --------

template <bool LAST>
__global__ void gcn_layer64(const _Float16* __restrict__ hs_in,
                            const float* __restrict__ W, const float* __restrict__ b,
                            const int* __restrict__ row_ptr, const int* __restrict__ col_src,
                            const float* __restrict__ dinv, const float* __restrict__ rdinv,
                            const float* __restrict__ wse, const float* __restrict__ wde,
                            int n,
                            _Float16* __restrict__ hout,
                            float4* __restrict__ a_src4, float4* __restrict__ a_dst4) {
    __shared__ float Wl[64 * 64];
    int tid = threadIdx.x;
    for (int i = tid; i < 4096; i += 256) Wl[i] = W[i];
    __syncthreads();
    int lane = tid & 63, wid = tid >> 6;
    int node = blockIdx.x * 4 + wid;
    if (node >= n) return;
    int t = lane & 7, g = lane >> 3;   // 8 edge slots x 8-channel chunks
    const half8* hs8 = (const half8*)hs_in;
    int beg = row_ptr[node], end = row_ptr[node + 1];
    int deg = end - beg;
    half8 sv = hs8[node * 8 + t];
    float ac[8];
#pragma unroll
    for (int c = 0; c < 8; ++c) ac[c] = (g == 0) ? (float)sv[c] : 0.f;
    for (int base = 0; base < deg; base += 64) {
        int cs = col_src[min(beg + base + lane, end - 1)];
        int lim = min(deg - base, 64);
        for (int chunk = 0; chunk < lim; chunk += 16) {
#pragma unroll
            for (int u = 0; u < 2; ++u) {
                int eo = chunk + u * 8 + g;
                int s = __shfl(cs, eo);
                half8 v = hs8[s * 8 + t];
                if (eo < lim) {
#pragma unroll
                    for (int c = 0; c < 8; ++c) ac[c] += (float)v[c];
                }
            }
        }
    }
#pragma unroll
    for (int c = 0; c < 8; ++c) {
        ac[c] += __shfl_xor(ac[c], 8);
        ac[c] += __shfl_xor(ac[c], 16);
        ac[c] += __shfl_xor(ac[c], 32);
    }
    float di = dinv[node];
#pragma unroll
    for (int c = 0; c < 8; ++c) ac[c] *= di;
    // dense: channel k lives on lane (k>>3), slot (k&7)
    float sum = b[lane];
#pragma unroll
    for (int k = 0; k < 64; ++k) {
        float av = __shfl(ac[k & 7], k >> 3);
        sum = fmaf(av, Wl[k * 64 + lane], sum);
    }
    float hprev = rdinv[node] * (float)hs_in[node * 64 + lane];
    float hv = hprev + fmaxf(sum, 0.f);
    if (!LAST) {
        hout[node * 64 + lane] = (_Float16)(di * hv);   // prescaled for next gather
    } else {
        hout[node * 64 + lane] = (_Float16)hv;          // raw h3 for GAT
        const float4* wse4 = (const float4*)wse;
        const float4* wde4 = (const float4*)wde;
        float4 we = wse4[lane], wd = wde4[lane];
        float vs[4] = {hv * we.x, hv * we.y, hv * we.z, hv * we.w};
        float vd[4] = {hv * wd.x, hv * wd.y, hv * wd.z, hv * wd.w};
#pragma unroll
        for (int m = 32; m > 0; m >>= 1) {
#pragma unroll
            for (int h = 0; h < 4; ++h) {
                vs[h] += __shfl_xor(vs[h], m);
                vd[h] += __shfl_xor(vd[h], m);
            }
        }
        if (lane == 0) {
            a_src4[node] = make_float4(vs[0], vs[1], vs[2], vs[3]);
            a_dst4[node] = make_float4(vd[0], vd[1], vd[2], vd[3]);
        }
    }
}

// ---- GAT aggregate: 1 node/wave, 8 edges per chunk-instr ------------------

__global__ void gat_agg(const _Float16* __restrict__ h3,
                        const float4* __restrict__ a_src4, const float4* __restrict__ a_dst4,
                        const int* __restrict__ row_ptr, const int* __restrict__ col_src,
                        int nbase, int ncount, float* __restrict__ aggout) {
    int tid = threadIdx.x, lane = tid & 63, wid = tid >> 6;
    int li = blockIdx.x * 4 + wid;
    if (li >= ncount) return;
    int node = nbase + li;
    int t = lane & 7, g = lane >> 3;
    const half8* h38 = (const half8*)h3;

    float4 ad = a_dst4[node];
    float4 asf = a_src4[node];
    half8 hself = h38[node * 8 + t];
    float A[4][8], dh[4];
    {
        float w0 = __expf(leaky02(asf.x + ad.x));
        float w1 = __expf(leaky02(asf.y + ad.y));
        float w2 = __expf(leaky02(asf.z + ad.z));
        float w3 = __expf(leaky02(asf.w + ad.w));
        float m0 = (g == 0) ? 1.f : 0.f;
        dh[0] = m0 * w0; dh[1] = m0 * w1; dh[2] = m0 * w2; dh[3] = m0 * w3;
#pragma unroll
        for (int c = 0; c < 8; ++c) {
            float hvc = (float)hself[c];
            A[0][c] = dh[0] * hvc;
            A[1][c] = dh[1] * hvc;
            A[2][c] = dh[2] * hvc;
            A[3][c] = dh[3] * hvc;
        }
    }
    int beg = row_ptr[node], end = row_ptr[node + 1];
    int deg = end - beg;
    for (int base = 0; base < deg; base += 64) {
        int cs = col_src[min(beg + base + lane, end - 1)];
        int lim = min(deg - base, 64);
        for (int chunk = 0; chunk < lim; chunk += 16) {
#pragma unroll
            for (int u = 0; u < 2; ++u) {
                int eo = chunk + u * 8 + g;
                int s = __shfl(cs, eo);
                float4 as = a_src4[s];
                half8 hv = h38[s * 8 + t];
                float valid = (eo < lim) ? 1.f : 0.f;
                float w0 = valid * __expf(leaky02(as.x + ad.x));
                float w1 = valid * __expf(leaky02(as.y + ad.y));
                float w2 = valid * __expf(leaky02(as.z + ad.z));
                float w3 = valid * __expf(leaky02(as.w + ad.w));
#pragma unroll
                for (int c = 0; c < 8; ++c) {
                    float hvc = (float)hv[c];
                    A[0][c] = fmaf(w0, hvc, A[0][c]);
                    A[1][c] = fmaf(w1, hvc, A[1][c]);
                    A[2][c] = fmaf(w2, hvc, A[2][c]);
                    A[3][c] = fmaf(w3, hvc, A[3][c]);
                }
                dh[0] += w0; dh[1] += w1; dh[2] += w2; dh[3] += w3;
            }
        }
    }
#pragma unroll
    for (int h = 0; h < 4; ++h) {
#pragma unroll
        for (int c = 0; c < 8; ++c) {
            A[h][c] += __shfl_xor(A[h][c], 8);
            A[h][c] += __shfl_xor(A[h][c], 16);
            A[h][c] += __shfl_xor(A[h][c], 32);
        }
        dh[h] += __shfl_xor(dh[h], 8);
        dh[h] += __shfl_xor(dh[h], 16);
        dh[h] += __shfl_xor(dh[h], 32);
    }
    // lanes g=0..3 store head g, channels t*8..t*8+7
    if (g < 4) {
        float r = 1.f / (dh[g] + 1e-16f);
        float* dst = aggout + (size_t)li * 256 + g * 64 + t * 8;
        float4 v0 = make_float4(A[g][0] * r, A[g][1] * r, A[g][2] * r, A[g][3] * r);
        float4 v1 = make_float4(A[g][4] * r, A[g][5] * r, A[g][6] * r, A[g][7] * r);
        *(float4*)dst = v0;
        *(float4*)(dst + 4) = v1;
    }
}

// ---- MLP: Ccomb staged in LDS once/block, 4 nodes/wave --------------------

__global__ __launch_bounds__(256) void mlp_kernel(
        const float* __restrict__ agg,
        const float* __restrict__ Ccomb, const float* __restrict__ bcomb,
        const float* __restrict__ wc2, const float* __restrict__ bc2,
        int nbase, int ncount, float* __restrict__ out) {
    __shared__ float Cl[256 * 64];
    int tid = threadIdx.x;
    {
        const float4* C4 = (const float4*)Ccomb;
        float4* Cl4 = (float4*)Cl;
        for (int i = tid; i < 4096; i += 256) Cl4[i] = C4[i];
    }
    __syncthreads();
    int lane = tid & 63;
    int wid = __builtin_amdgcn_readfirstlane(tid >> 6);
    int nwaves = gridDim.x * 4;
    int gw = blockIdx.x * 4 + wid;
    float bz = bcomb[lane];
    float w20 = wc2[lane * 3 + 0], w21 = wc2[lane * 3 + 1], w22 = wc2[lane * 3 + 2];
    float bb0 = bc2[0], bb1 = bc2[1], bb2 = bc2[2];
    int nquads = (ncount + 3) >> 2;
    int limax = ncount - 1;
    for (int qd = gw; qd < nquads; qd += nwaves) {
        int l0 = min(qd * 4 + 0, limax);
        int l1 = min(qd * 4 + 1, limax);
        int l2 = min(qd * 4 + 2, limax);
        int l3 = min(qd * 4 + 3, limax);
        const float* a0 = agg + (size_t)l0 * 256;
        const float* a1 = agg + (size_t)l1 * 256;
        const float* a2 = agg + (size_t)l2 * 256;
        const float* a3 = agg + (size_t)l3 * 256;
        float z0 = bz, z1 = bz, z2 = bz, z3 = bz;
#pragma unroll 16
        for (int i = 0; i < 256; ++i) {
            float c = Cl[i * 64 + lane];
            z0 = fmaf(a0[i], c, z0);
            z1 = fmaf(a1[i], c, z1);
            z2 = fmaf(a2[i], c, z2);
            z3 = fmaf(a3[i], c, z3);
        }
        z0 = fmaxf(z0, 0.f); z1 = fmaxf(z1, 0.f);
        z2 = fmaxf(z2, 0.f); z3 = fmaxf(z3, 0.f);
        float p[12];
        p[0] = z0 * w20; p[1] = z0 * w21; p[2] = z0 * w22;
        p[3] = z1 * w20; p[4] = z1 * w21; p[5] = z1 * w22;
        p[6] = z2 * w20; p[7] = z2 * w21; p[8] = z2 * w22;
        p[9] = z3 * w20; p[10] = z3 * w21; p[11] = z3 * w22;
#pragma unroll
        for (int m = 32; m > 0; m >>= 1) {
#pragma unroll
            for (int tt = 0; tt < 12; ++tt) p[tt] += __shfl_xor(p[tt], m);
        }
        if (lane == 0) {
            int ls[4] = {l0, l1, l2, l3};
#pragma unroll
            for (int m = 0; m < 4; ++m) {
                float e0 = p[m * 3 + 0] + bb0, e1 = p[m * 3 + 1] + bb1, e2 = p[m * 3 + 2] + bb2;
                float mx = fmaxf(e0, fmaxf(e1, e2));
                float lse = mx + logf(expf(e0 - mx) + expf(e1 - mx) + expf(e2 - mx));
                int nn = nbase + ls[m];
                out[nn * 3 + 0] = e0 - lse;
                out[nn * 3 + 1] = e1 - lse;
                out[nn * 3 + 2] = e2 - lse;
            }
        }
    }
}

// ---------------------------------------------------------------------------

extern "C" void kernel_launch(void* const* d_in, const int* in_sizes, int n_in,
                              void* d_out, int out_size, void* d_ws, size_t ws_size,
                              hipStream_t stream) {
    const float* x       = (const float*)d_in[0];
    const int*   ei      = (const int*)d_in[1];
    const float* w1      = (const float*)d_in[2];
    const float* b1      = (const float*)d_in[3];
    const float* w2      = (const float*)d_in[4];
    const float* b2      = (const float*)d_in[5];
    const float* w3      = (const float*)d_in[6];
    const float* b3      = (const float*)d_in[7];
    const float* wg      = (const float*)d_in[8];
    const float* bg      = (const float*)d_in[9];
    const float* att_s   = (const float*)d_in[10];
    const float* att_d   = (const float*)d_in[11];
    const float* wc1     = (const float*)d_in[12];
    const float* bc1     = (const float*)d_in[13];
    const float* wc2     = (const float*)d_in[14];
    const float* bc2     = (const float*)d_in[15];
    float* out = (float*)d_out;

    const int N = in_sizes[0] / 8;
    const int E = in_sizes[1] / 2;
    const int* srcv = ei;
    const int* dstv = ei + E;

    char* ws = (char*)d_ws;
    size_t off = 0;
    auto alloc = [&](size_t bytes) -> char* {
        char* p = ws + off;
        off += (bytes + 255) & ~(size_t)255;
        return p;
    };
    int*      counts    = (int*)alloc((size_t)N * 4);
    int*      row_ptr   = (int*)alloc((size_t)(N + 1) * 4);
    int*      cursor    = (int*)alloc((size_t)N * 4);
    int*      col_src   = (int*)alloc((size_t)E * 4);
    int*      blockSums = (int*)alloc(4096 * 4);
    int*      blockOffs = (int*)alloc(4096 * 4);
    float*    dinv      = (float*)alloc((size_t)N * 4);
    float*    rdinv     = (float*)alloc((size_t)N * 4);
    _Float16* xs        = (_Float16*)alloc((size_t)N * 8 * 2);
    float*    a_src     = (float*)alloc((size_t)N * 16);
    float*    a_dst     = (float*)alloc((size_t)N * 16);
    float*    wse       = (float*)alloc(256 * 4);
    float*    wde       = (float*)alloc(256 * 4);
    float*    Ccomb     = (float*)alloc(256 * 64 * 4);
    float*    bcomb     = (float*)alloc(64 * 4);
    _Float16* bufA      = (_Float16*)alloc((size_t)N * 64 * 2);  // hs1, later h3
    _Float16* bufB      = (_Float16*)alloc((size_t)N * 64 * 2);  // hs2
    const int S = (N + 3) / 4;                                   // stripe size
    float*    aggbuf    = (float*)alloc((size_t)S * 256 * 4);
    _Float16* hs1 = bufA;
    _Float16* hs2 = bufB;
    _Float16* h3  = bufA;   // hs1 dead once layer3 runs (layer3 reads hs2 only)
    (void)ws_size; (void)n_in; (void)out_size;

    hipMemsetAsync(counts, 0, (size_t)N * 4, stream);

    const int TPB = 256;
    int gridE = (E + TPB - 1) / TPB;
    count_kernel<<<gridE, TPB, 0, stream>>>(dstv, E, counts);

    int NB = (N + 2047) / 2048;
    scan_pass1<<<NB, TPB, 0, stream>>>(counts, N, blockSums);
    scan_pass2<<<1, 64, 0, stream>>>(blockSums, NB, blockOffs);
    scan_pass3<<<NB, TPB, 0, stream>>>(counts, N, blockOffs, x,
                                       row_ptr, cursor, dinv, rdinv, xs);
    scatter_kernel<<<gridE, TPB, 0, stream>>>(srcv, dstv, E, cursor, col_src);

    att_eff_kernel<<<1, TPB, 0, stream>>>(wg, att_s, att_d, wse, wde);
    ccomb_kernel<<<257, 64, 0, stream>>>(wg, bg, wc1, bc1, Ccomb, bcomb);

    int gridN = (N + 3) / 4;
    gcn_layer1<<<gridN, TPB, 0, stream>>>((const half8*)xs, w1, b1, row_ptr, col_src,
                                          dinv, N, hs1);
    gcn_layer64<false><<<gridN, TPB, 0, stream>>>(hs1, w2, b2, row_ptr, col_src,
                                                  dinv, rdinv, wse, wde, N, hs2,
                                                  nullptr, nullptr);
    gcn_layer64<true><<<gridN, TPB, 0, stream>>>(hs2, w3, b3, row_ptr, col_src,
                                                 dinv, rdinv, wse, wde, N, h3,
                                                 (float4*)a_src, (float4*)a_dst);

    // GAT + MLP in 4 stripes reusing the agg slab
    for (int s = 0; s < 4; ++s) {
        int nbase = s * S;
        if (nbase >= N) break;
        int ncount = min(S, N - nbase);
        int gridA = (ncount + 3) / 4;   // 1 node per wave
        gat_agg<<<gridA, TPB, 0, stream>>>(h3, (const float4*)a_src, (const float4*)a_dst,
                                           row_ptr, col_src, nbase, ncount, aggbuf);
        mlp_kernel<<<512, TPB, 0, stream>>>(aggbuf, Ccomb, bcomb, wc2, bc2,
                                            nbase, ncount, out);
    }
}

// Round 7
// 846.590 us; speedup vs baseline: 1.2650x; 1.2650x over previous
//
#include <hip/hip_runtime.h>
#include <math.h>

// ---------------------------------------------------------------------------
// SpatialGNN: 3x GCN (residual) + 4-head GAT + MLP + log_softmax
// N=100000, E=1600000, IN=8, HID=64, HEADS=4, OUT=3
//
// R6 changes vs R5 (DS-pipe attack — R5/R6 showed duration invariant to
// FETCH halving; __shfl lowers to ds_bpermute and the dense loops issued
// ~144 DS ops/node, saturating the LDS pipe at ~5.8cyc/op):
//  - gcn_layer64: W column kept in VGPRs (64 coalesced loads once per wave,
//    grid-stride ~24 nodes/wave); agg broadcast via 16 ds_read_b128
//    same-address reads. DS/node 144 -> ~28.
//  - Edge-group moved to LOW lane bits (g=lane&7): group reduction = xor1/2/4;
//    xor1/2 via DPP quad_perm (VALU-pipe), only xor4 on DS. gat_agg reduction
//    108 -> 36 DS/node.
//  - mlp: 4-wave split; each wave holds 64 Ccomb rows in VGPRs, agg rows are
//    wave-uniform scalar loads, partials via 4KB LDS. DS/node 64 -> ~17.
//  - Explicit DPP/swizzle reduction helpers replace __shfl_xor butterflies.
//  - att_eff merged into ccomb kernel.
// ---------------------------------------------------------------------------

typedef _Float16 half8 __attribute__((ext_vector_type(8)));

__device__ __forceinline__ float leaky02(float v) { return v > 0.f ? v : 0.2f * v; }

// ---- cross-lane reduction helpers ----------------------------------------
// xor1/xor2 = DPP quad_perm (VALU pipe); xor8 = DPP row_ror:8;
// xor4/xor16 = ds_swizzle; xor32 = ds_bpermute (__shfl_xor).

template <int CTRL>
__device__ __forceinline__ float dpp_add(float v) {
    int iv = __builtin_bit_cast(int, v);
    int r = __builtin_amdgcn_update_dpp(iv, iv, CTRL, 0xF, 0xF, false);
    return v + __builtin_bit_cast(float, r);
}
template <int OFF>
__device__ __forceinline__ float swz_add(float v) {
    int r = __builtin_amdgcn_ds_swizzle(__builtin_bit_cast(int, v), OFF);
    return v + __builtin_bit_cast(float, r);
}
// sum over lanes differing in bits 0..2 (groups of 8)
__device__ __forceinline__ float red8(float v) {
    v = dpp_add<0xB1>(v);     // xor1: quad_perm(1,0,3,2)
    v = dpp_add<0x4E>(v);     // xor2: quad_perm(2,3,0,1)
    v = swz_add<0x101F>(v);   // xor4
    return v;
}
// full 64-lane sum
__device__ __forceinline__ float red64(float v) {
    v = dpp_add<0xB1>(v);
    v = dpp_add<0x4E>(v);
    v = swz_add<0x101F>(v);
    v = dpp_add<0x128>(v);    // xor8: row_ror:8
    v = swz_add<0x401F>(v);   // xor16
    v = v + __shfl_xor(v, 32);
    return v;
}
__device__ __forceinline__ float sel4(int g, float v0, float v1, float v2, float v3) {
    return g == 0 ? v0 : g == 1 ? v1 : g == 2 ? v2 : v3;
}

// ---- CSR build ------------------------------------------------------------

__global__ void count_kernel(const int* __restrict__ dst, int E, int* __restrict__ counts) {
    int e = blockIdx.x * blockDim.x + threadIdx.x;
    if (e < E) atomicAdd(&counts[dst[e]], 1);
}

__global__ void scan_pass1(const int* __restrict__ counts, int n, int* __restrict__ blockSums) {
    __shared__ int sh[256];
    int base = blockIdx.x * 2048;
    int tid = threadIdx.x;
    int s = 0;
#pragma unroll
    for (int j = 0; j < 8; ++j) {
        int idx = base + tid * 8 + j;
        if (idx < n) s += counts[idx];
    }
    sh[tid] = s;
    __syncthreads();
    for (int off = 128; off > 0; off >>= 1) {
        if (tid < off) sh[tid] += sh[tid + off];
        __syncthreads();
    }
    if (tid == 0) blockSums[blockIdx.x] = sh[0];
}

__global__ void scan_pass2(const int* __restrict__ blockSums, int nb, int* __restrict__ blockOffs) {
    if (threadIdx.x == 0 && blockIdx.x == 0) {
        int run = 0;
        for (int i = 0; i < nb; ++i) { blockOffs[i] = run; run += blockSums[i]; }
    }
}

__global__ void scan_pass3(const int* __restrict__ counts, int n,
                           const int* __restrict__ blockOffs,
                           const float* __restrict__ x,
                           int* __restrict__ row_ptr, int* __restrict__ cursor,
                           float* __restrict__ dinv, float* __restrict__ rdinv,
                           _Float16* __restrict__ xs) {
    __shared__ int sh[256];
    int base = blockIdx.x * 2048;
    int tid = threadIdx.x;
    int cnt[8];
    int local = 0;
#pragma unroll
    for (int j = 0; j < 8; ++j) {
        int idx = base + tid * 8 + j;
        cnt[j] = (idx < n) ? counts[idx] : 0;
        local += cnt[j];
    }
    sh[tid] = local;
    __syncthreads();
    for (int off = 1; off < 256; off <<= 1) {
        int v = (tid >= off) ? sh[tid - off] : 0;
        __syncthreads();
        sh[tid] += v;
        __syncthreads();
    }
    int run = blockOffs[blockIdx.x] + sh[tid] - local;
#pragma unroll
    for (int j = 0; j < 8; ++j) {
        int idx = base + tid * 8 + j;
        if (idx < n) {
            row_ptr[idx] = run;
            cursor[idx] = run;
            float dv = rsqrtf((float)(cnt[j] + 1));
            dinv[idx] = dv;
            rdinv[idx] = sqrtf((float)(cnt[j] + 1));
#pragma unroll
            for (int t = 0; t < 8; ++t) xs[idx * 8 + t] = (_Float16)(dv * x[idx * 8 + t]);
            run += cnt[j];
            if (idx == n - 1) row_ptr[n] = run;
        }
    }
}

__global__ void scatter_kernel(const int* __restrict__ src, const int* __restrict__ dst, int E,
                               int* __restrict__ cursor, int* __restrict__ col_src) {
    int e = blockIdx.x * blockDim.x + threadIdx.x;
    if (e < E) {
        int d = dst[e];
        int pos = atomicAdd(&cursor[d], 1);
        col_src[pos] = src[e];
    }
}

// ---- weight precompute: Ccomb/bcomb + attention-effective vectors ---------

__global__ void ccomb_kernel(const float* __restrict__ Wg, const float* __restrict__ bg,
                             const float* __restrict__ wc1, const float* __restrict__ bc1,
                             const float* __restrict__ att_src, const float* __restrict__ att_dst,
                             float* __restrict__ Ccomb, float* __restrict__ bcomb,
                             float* __restrict__ wse, float* __restrict__ wde) {
    int bid = blockIdx.x;   // 0..256
    int j = threadIdx.x;    // 64 threads
    if (bid < 256) {
        int h = bid >> 6, k = bid & 63;
        float s = 0.f;
        for (int c = 0; c < 64; ++c)
            s += Wg[k * 256 + h * 64 + c] * wc1[(h * 64 + c) * 64 + j];
        Ccomb[bid * 64 + j] = s;
    } else {
        float s = bc1[j];
        for (int i = 0; i < 256; ++i) s += bg[i] * wc1[i * 64 + j];
        bcomb[j] = s;
#pragma unroll
        for (int h = 0; h < 4; ++h) {
            float ss = 0.f, sd = 0.f;
            for (int c = 0; c < 64; ++c) {
                float w = Wg[j * 256 + h * 64 + c];
                ss += w * att_src[h * 64 + c];
                sd += w * att_dst[h * 64 + c];
            }
            wse[j * 4 + h] = ss;
            wde[j * 4 + h] = sd;
        }
    }
}

// ---- GCN layer 1: one edge per lane (16B half8 row) -----------------------

__global__ void gcn_layer1(const half8* __restrict__ xs8,
                           const float* __restrict__ W1, const float* __restrict__ b1,
                           const int* __restrict__ row_ptr, const int* __restrict__ col_src,
                           const float* __restrict__ dinv, int n,
                           _Float16* __restrict__ hs1) {
    int tid = threadIdx.x, lane = tid & 63, wid = tid >> 6;
    int node = blockIdx.x * 4 + wid;
    if (node >= n) return;
    int beg = row_ptr[node], end = row_ptr[node + 1];
    int deg = end - beg;
    float acc[8] = {0.f, 0.f, 0.f, 0.f, 0.f, 0.f, 0.f, 0.f};
    for (int base = 0; base < deg; base += 64) {
        int cs = col_src[min(beg + base + lane, end - 1)];
        half8 v = xs8[cs];
        if (base + lane < deg) {
#pragma unroll
            for (int c = 0; c < 8; ++c) acc[c] += (float)v[c];
        }
    }
#pragma unroll
    for (int c = 0; c < 8; ++c) acc[c] = red64(acc[c]);
    half8 sv = xs8[node];
    float di = dinv[node];
    float agg[8];
#pragma unroll
    for (int c = 0; c < 8; ++c) agg[c] = (acc[c] + (float)sv[c]) * di;
    float sum = b1[lane];
#pragma unroll
    for (int k = 0; k < 8; ++k) sum = fmaf(agg[k], W1[k * 64 + lane], sum);
    hs1[node * 64 + lane] = (_Float16)(di * fmaxf(sum, 0.f));
}

// ---- GCN layer 2/3: g=lane&7 edge slots, t=lane>>3 channel chunks ---------
// Dense transform: W column in VGPRs + LDS b128 broadcast of agg.

template <bool LAST>
__global__ void gcn_layer64(const _Float16* __restrict__ hs_in,
                            const float* __restrict__ W, const float* __restrict__ b,
                            const int* __restrict__ row_ptr, const int* __restrict__ col_src,
                            const float* __restrict__ dinv, const float* __restrict__ rdinv,
                            const float* __restrict__ wse, const float* __restrict__ wde,
                            int n,
                            _Float16* __restrict__ hout,
                            float4* __restrict__ a_src4, float4* __restrict__ a_dst4) {
    __shared__ float agg_lds[4][64];
    int tid = threadIdx.x;
    int lane = tid & 63;
    int wid = tid >> 6;
    int t = lane >> 3, g = lane & 7;
    const half8* hs8 = (const half8*)hs_in;
    // W column (all 64 k for this lane's output channel) in VGPRs
    float wreg[64];
#pragma unroll
    for (int k = 0; k < 64; ++k) wreg[k] = W[k * 64 + lane];
    float bl = b[lane];
    float4 we, wd;
    if (LAST) {
        we = ((const float4*)wse)[lane];
        wd = ((const float4*)wde)[lane];
    }
    int nw = gridDim.x * 4;
    for (int node = blockIdx.x * 4 + wid; node < n; node += nw) {
        int beg = row_ptr[node], end = row_ptr[node + 1];
        int deg = end - beg;
        half8 sv = hs8[node * 8 + t];
        float ac[8];
#pragma unroll
        for (int c = 0; c < 8; ++c) ac[c] = (g == 0) ? (float)sv[c] : 0.f;
        for (int base = 0; base < deg; base += 64) {
            int cs = col_src[min(beg + base + lane, end - 1)];
            int lim = min(deg - base, 64);
            for (int chunk = 0; chunk < lim; chunk += 16) {
#pragma unroll
                for (int u = 0; u < 2; ++u) {
                    int eo = chunk + u * 8 + g;
                    int s = __shfl(cs, eo);
                    half8 v = hs8[s * 8 + t];
                    if (eo < lim) {
#pragma unroll
                        for (int c = 0; c < 8; ++c) ac[c] += (float)v[c];
                    }
                }
            }
        }
        float di = dinv[node];
#pragma unroll
        for (int c = 0; c < 8; ++c) ac[c] = red8(ac[c]) * di;   // xor1/2 DPP + xor4 DS
        if (g == 0) {   // lanes 0,8,..,56 hold chunks t=0..7
            *(float4*)&agg_lds[wid][t * 8]     = make_float4(ac[0], ac[1], ac[2], ac[3]);
            *(float4*)&agg_lds[wid][t * 8 + 4] = make_float4(ac[4], ac[5], ac[6], ac[7]);
        }
        __asm__ volatile("s_waitcnt lgkmcnt(0)" ::: "memory");
        float sum = bl;
#pragma unroll
        for (int k4 = 0; k4 < 16; ++k4) {
            float4 a4 = *(const float4*)&agg_lds[wid][k4 * 4];  // same-addr b128 broadcast
            sum = fmaf(a4.x, wreg[k4 * 4 + 0], sum);
            sum = fmaf(a4.y, wreg[k4 * 4 + 1], sum);
            sum = fmaf(a4.z, wreg[k4 * 4 + 2], sum);
            sum = fmaf(a4.w, wreg[k4 * 4 + 3], sum);
        }
        float hprev = rdinv[node] * (float)hs_in[node * 64 + lane];
        float hv = hprev + fmaxf(sum, 0.f);
        if (!LAST) {
            hout[node * 64 + lane] = (_Float16)(di * hv);   // prescaled for next gather
        } else {
            hout[node * 64 + lane] = (_Float16)hv;          // raw h3 for GAT
            float vs0 = red64(hv * we.x), vs1 = red64(hv * we.y);
            float vs2 = red64(hv * we.z), vs3 = red64(hv * we.w);
            float vd0 = red64(hv * wd.x), vd1 = red64(hv * wd.y);
            float vd2 = red64(hv * wd.z), vd3 = red64(hv * wd.w);
            if (lane == 0) {
                a_src4[node] = make_float4(vs0, vs1, vs2, vs3);
                a_dst4[node] = make_float4(vd0, vd1, vd2, vd3);
            }
        }
    }
}

// ---- GAT aggregate: g=lane&7 edge slots, reductions mostly DPP ------------

__global__ void gat_agg(const _Float16* __restrict__ h3,
                        const float4* __restrict__ a_src4, const float4* __restrict__ a_dst4,
                        const int* __restrict__ row_ptr, const int* __restrict__ col_src,
                        int nbase, int ncount, float* __restrict__ aggout) {
    int tid = threadIdx.x, lane = tid & 63, wid = tid >> 6;
    int li = blockIdx.x * 4 + wid;
    if (li >= ncount) return;
    int node = nbase + li;
    int t = lane >> 3, g = lane & 7;
    const half8* h38 = (const half8*)h3;

    float4 ad = a_dst4[node];
    float4 asf = a_src4[node];
    half8 hself = h38[node * 8 + t];
    float A[4][8], dh[4];
    {
        float w0 = __expf(leaky02(asf.x + ad.x));
        float w1 = __expf(leaky02(asf.y + ad.y));
        float w2 = __expf(leaky02(asf.z + ad.z));
        float w3 = __expf(leaky02(asf.w + ad.w));
        float m0 = (g == 0) ? 1.f : 0.f;
        dh[0] = m0 * w0; dh[1] = m0 * w1; dh[2] = m0 * w2; dh[3] = m0 * w3;
#pragma unroll
        for (int c = 0; c < 8; ++c) {
            float hvc = (float)hself[c];
            A[0][c] = dh[0] * hvc;
            A[1][c] = dh[1] * hvc;
            A[2][c] = dh[2] * hvc;
            A[3][c] = dh[3] * hvc;
        }
    }
    int beg = row_ptr[node], end = row_ptr[node + 1];
    int deg = end - beg;
    for (int base = 0; base < deg; base += 64) {
        int cs = col_src[min(beg + base + lane, end - 1)];
        int lim = min(deg - base, 64);
        for (int chunk = 0; chunk < lim; chunk += 16) {
#pragma unroll
            for (int u = 0; u < 2; ++u) {
                int eo = chunk + u * 8 + g;
                int s = __shfl(cs, eo);
                float4 as = a_src4[s];
                half8 hv = h38[s * 8 + t];
                float valid = (eo < lim) ? 1.f : 0.f;
                float w0 = valid * __expf(leaky02(as.x + ad.x));
                float w1 = valid * __expf(leaky02(as.y + ad.y));
                float w2 = valid * __expf(leaky02(as.z + ad.z));
                float w3 = valid * __expf(leaky02(as.w + ad.w));
#pragma unroll
                for (int c = 0; c < 8; ++c) {
                    float hvc = (float)hv[c];
                    A[0][c] = fmaf(w0, hvc, A[0][c]);
                    A[1][c] = fmaf(w1, hvc, A[1][c]);
                    A[2][c] = fmaf(w2, hvc, A[2][c]);
                    A[3][c] = fmaf(w3, hvc, A[3][c]);
                }
                dh[0] += w0; dh[1] += w1; dh[2] += w2; dh[3] += w3;
            }
        }
    }
#pragma unroll
    for (int h = 0; h < 4; ++h) {
#pragma unroll
        for (int c = 0; c < 8; ++c) A[h][c] = red8(A[h][c]);
        dh[h] = red8(dh[h]);
    }
    float r0 = 1.f / (dh[0] + 1e-16f);
    float r1 = 1.f / (dh[1] + 1e-16f);
    float r2 = 1.f / (dh[2] + 1e-16f);
    float r3 = 1.f / (dh[3] + 1e-16f);
    // lanes with g<4 write head g, channels t*8..t*8+7 (compile-time-safe sel4)
    if (g < 4) {
        float r = sel4(g, r0, r1, r2, r3);
        float4 v0, v1;
        v0.x = sel4(g, A[0][0], A[1][0], A[2][0], A[3][0]) * r;
        v0.y = sel4(g, A[0][1], A[1][1], A[2][1], A[3][1]) * r;
        v0.z = sel4(g, A[0][2], A[1][2], A[2][2], A[3][2]) * r;
        v0.w = sel4(g, A[0][3], A[1][3], A[2][3], A[3][3]) * r;
        v1.x = sel4(g, A[0][4], A[1][4], A[2][4], A[3][4]) * r;
        v1.y = sel4(g, A[0][5], A[1][5], A[2][5], A[3][5]) * r;
        v1.z = sel4(g, A[0][6], A[1][6], A[2][6], A[3][6]) * r;
        v1.w = sel4(g, A[0][7], A[1][7], A[2][7], A[3][7]) * r;
        float* dst = aggout + (size_t)li * 256 + g * 64 + t * 8;
        *(float4*)dst = v0;
        *(float4*)(dst + 4) = v1;
    }
}

// ---- MLP: Ccomb rows in VGPRs (4-wave split), agg via scalar loads --------

__global__ __launch_bounds__(256) void mlp_kernel(
        const float* __restrict__ agg,
        const float* __restrict__ Ccomb, const float* __restrict__ bcomb,
        const float* __restrict__ wc2, const float* __restrict__ bc2,
        int nbase, int ncount, float* __restrict__ out) {
    __shared__ float part[4][4][64];   // [node-in-chunk][wave][lane]
    int tid = threadIdx.x;
    int lane = tid & 63;
    int w = __builtin_amdgcn_readfirstlane(tid >> 6);
    // this wave's 64-row slice of Ccomb in VGPRs
    float creg[64];
#pragma unroll
    for (int i = 0; i < 64; ++i) creg[i] = Ccomb[(w * 64 + i) * 64 + lane];
    float bz = bcomb[lane];
    float w20 = wc2[lane * 3 + 0], w21 = wc2[lane * 3 + 1], w22 = wc2[lane * 3 + 2];
    float bb0 = bc2[0], bb1 = bc2[1], bb2 = bc2[2];
    int nchunks = (ncount + 3) >> 2;
    for (int ch = blockIdx.x; ch < nchunks; ch += gridDim.x) {
        int base = ch * 4;
        // phase 1: each wave computes its i-slice partial for 4 nodes
#pragma unroll
        for (int j = 0; j < 4; ++j) {
            int li = min(base + j, ncount - 1);
            const float* a = agg + (size_t)li * 256 + w * 64;   // wave-uniform -> s_load
            float p = 0.f;
#pragma unroll
            for (int i = 0; i < 64; ++i) p = fmaf(a[i], creg[i], p);
            part[j][w][lane] = p;
        }
        __syncthreads();
        // phase 2: wave w finishes node base+w
        int li = base + w;
        if (li < ncount) {
            float z = bz + part[w][0][lane] + part[w][1][lane]
                         + part[w][2][lane] + part[w][3][lane];
            z = fmaxf(z, 0.f);
            float p0 = red64(z * w20);
            float p1 = red64(z * w21);
            float p2 = red64(z * w22);
            if (lane == 0) {
                float e0 = p0 + bb0, e1 = p1 + bb1, e2 = p2 + bb2;
                float mx = fmaxf(e0, fmaxf(e1, e2));
                float lse = mx + logf(expf(e0 - mx) + expf(e1 - mx) + expf(e2 - mx));
                int nn = nbase + li;
                out[nn * 3 + 0] = e0 - lse;
                out[nn * 3 + 1] = e1 - lse;
                out[nn * 3 + 2] = e2 - lse;
            }
        }
        __syncthreads();
    }
}

// ---------------------------------------------------------------------------

extern "C" void kernel_launch(void* const* d_in, const int* in_sizes, int n_in,
                              void* d_out, int out_size, void* d_ws, size_t ws_size,
                              hipStream_t stream) {
    const float* x       = (const float*)d_in[0];
    const int*   ei      = (const int*)d_in[1];
    const float* w1      = (const float*)d_in[2];
    const float* b1      = (const float*)d_in[3];
    const float* w2      = (const float*)d_in[4];
    const float* b2      = (const float*)d_in[5];
    const float* w3      = (const float*)d_in[6];
    const float* b3      = (const float*)d_in[7];
    const float* wg      = (const float*)d_in[8];
    const float* bg      = (const float*)d_in[9];
    const float* att_s   = (const float*)d_in[10];
    const float* att_d   = (const float*)d_in[11];
    const float* wc1     = (const float*)d_in[12];
    const float* bc1     = (const float*)d_in[13];
    const float* wc2     = (const float*)d_in[14];
    const float* bc2     = (const float*)d_in[15];
    float* out = (float*)d_out;

    const int N = in_sizes[0] / 8;
    const int E = in_sizes[1] / 2;
    const int* srcv = ei;
    const int* dstv = ei + E;

    char* ws = (char*)d_ws;
    size_t off = 0;
    auto alloc = [&](size_t bytes) -> char* {
        char* p = ws + off;
        off += (bytes + 255) & ~(size_t)255;
        return p;
    };
    int*      counts    = (int*)alloc((size_t)N * 4);
    int*      row_ptr   = (int*)alloc((size_t)(N + 1) * 4);
    int*      cursor    = (int*)alloc((size_t)N * 4);
    int*      col_src   = (int*)alloc((size_t)E * 4);
    int*      blockSums = (int*)alloc(4096 * 4);
    int*      blockOffs = (int*)alloc(4096 * 4);
    float*    dinv      = (float*)alloc((size_t)N * 4);
    float*    rdinv     = (float*)alloc((size_t)N * 4);
    _Float16* xs        = (_Float16*)alloc((size_t)N * 8 * 2);
    float*    a_src     = (float*)alloc((size_t)N * 16);
    float*    a_dst     = (float*)alloc((size_t)N * 16);
    float*    wse       = (float*)alloc(256 * 4);
    float*    wde       = (float*)alloc(256 * 4);
    float*    Ccomb     = (float*)alloc(256 * 64 * 4);
    float*    bcomb     = (float*)alloc(64 * 4);
    _Float16* bufA      = (_Float16*)alloc((size_t)N * 64 * 2);  // hs1, later h3
    _Float16* bufB      = (_Float16*)alloc((size_t)N * 64 * 2);  // hs2
    const int S = (N + 3) / 4;                                   // stripe size
    float*    aggbuf    = (float*)alloc((size_t)S * 256 * 4);
    _Float16* hs1 = bufA;
    _Float16* hs2 = bufB;
    _Float16* h3  = bufA;   // hs1 dead once layer3 runs (layer3 reads hs2 only)
    (void)ws_size; (void)n_in; (void)out_size;

    hipMemsetAsync(counts, 0, (size_t)N * 4, stream);

    const int TPB = 256;
    int gridE = (E + TPB - 1) / TPB;
    count_kernel<<<gridE, TPB, 0, stream>>>(dstv, E, counts);

    int NB = (N + 2047) / 2048;
    scan_pass1<<<NB, TPB, 0, stream>>>(counts, N, blockSums);
    scan_pass2<<<1, 64, 0, stream>>>(blockSums, NB, blockOffs);
    scan_pass3<<<NB, TPB, 0, stream>>>(counts, N, blockOffs, x,
                                       row_ptr, cursor, dinv, rdinv, xs);
    scatter_kernel<<<gridE, TPB, 0, stream>>>(srcv, dstv, E, cursor, col_src);

    ccomb_kernel<<<257, 64, 0, stream>>>(wg, bg, wc1, bc1, att_s, att_d,
                                         Ccomb, bcomb, wse, wde);

    int gridN = (N + 3) / 4;
    gcn_layer1<<<gridN, TPB, 0, stream>>>((const half8*)xs, w1, b1, row_ptr, col_src,
                                          dinv, N, hs1);
    const int G64 = 1024;   // grid-stride: ~24 nodes/wave, amortizes W VGPR load
    gcn_layer64<false><<<G64, TPB, 0, stream>>>(hs1, w2, b2, row_ptr, col_src,
                                                dinv, rdinv, wse, wde, N, hs2,
                                                nullptr, nullptr);
    gcn_layer64<true><<<G64, TPB, 0, stream>>>(hs2, w3, b3, row_ptr, col_src,
                                               dinv, rdinv, wse, wde, N, h3,
                                               (float4*)a_src, (float4*)a_dst);

    // GAT + MLP in 4 stripes reusing the agg slab
    for (int s = 0; s < 4; ++s) {
        int nbase = s * S;
        if (nbase >= N) break;
        int ncount = min(S, N - nbase);
        int gridA = (ncount + 3) / 4;   // 1 node per wave
        gat_agg<<<gridA, TPB, 0, stream>>>(h3, (const float4*)a_src, (const float4*)a_dst,
                                           row_ptr, col_src, nbase, ncount, aggbuf);
        mlp_kernel<<<512, TPB, 0, stream>>>(aggbuf, Ccomb, bcomb, wc2, bc2,
                                            nbase, ncount, out);
    }
}